// Round 3
// baseline (220.054 us; speedup 1.0000x reference)
//
#include <hip/hip_runtime.h>

// Problem dims (fixed by reference)
#define T_TOTAL (32 * 4096)   // B*S = 131072 tokens
#define FDIM 256
#define NG 2                  // groups
#define NN 128                // entries per group
#define DDIM 128              // group dim
#define EDIM 256              // embed dim

#define TAU 0.004f            // bf16x3-vs-f32 safety margin for argmax gap
#define CAP 16384             // max flagged (t,g) entries (expected ~1k)

typedef __attribute__((ext_vector_type(4))) float f32x4;
typedef __attribute__((ext_vector_type(8))) short short8;

// ---------------------------------------------------------------------------
// Kernel P (prep): CO = codebooks @ W_out slices ; BT = split-bf16 W^T ;
// zero flag counter. One block per (g,n) = 256 blocks x 256 threads.
//   threads 128..255: wsplit for k = tid-128 (coalesced-enough scalar loads)
//   all 256 threads after sync: CO dot for e = tid
// ---------------------------------------------------------------------------
__global__ __launch_bounds__(256) void prep_kernel(
    const float* __restrict__ codebooks,  // [2][128][128]
    const float* __restrict__ W_out,      // [256][256]
    const float* __restrict__ Wl,         // [2][128 k][128 n]
    float* __restrict__ CO,               // [2][128][256]
    short* __restrict__ BT,               // [2 lev][2 g][128 n][128 k]
    int* __restrict__ flag_count)
{
    const int gn  = blockIdx.x;           // g*128 + n
    const int g   = gn >> 7;
    const int tid = threadIdx.x;
    __shared__ float cb[DDIM];
    if (tid < DDIM) cb[tid] = codebooks[gn * DDIM + tid];
    if (tid >= 128) {
        const int k = tid - 128;
        const int n = gn & 127;
        const float x = Wl[((size_t)g * DDIM + k) * NN + n];
        const unsigned u = __float_as_uint(x);
        const float hi = __uint_as_float(u & 0xffff0000u);
        const unsigned u2 = __float_as_uint(x - hi);   // exact residual
        BT[(size_t)g * 16384 + n * 128 + k] = (short)(u >> 16);
        BT[32768 + (size_t)g * 16384 + n * 128 + k] = (short)(u2 >> 16);
    }
    if (gn == 0 && tid == 0) *flag_count = 0;
    __syncthreads();
    float acc = 0.f;
    const float* wcol = W_out + (g * DDIM) * EDIM + tid;
#pragma unroll 4
    for (int d = 0; d < DDIM; ++d) acc += cb[d] * wcol[d * EDIM];
    CO[gn * EDIM + tid] = acc;
}

// ---------------------------------------------------------------------------
// Kernel B (main): logits^T = W_g x features^T via bf16x3 MFMA, fused
// gumbel argmax (per-lane, vectorized) + out-gather.
// Block: 512 threads = 8 waves. Wave w: g = w&1, token subtile th = w>>1.
// Wave computes 128 n x 16 tokens. D: col=lane&15 -> token, row=(lane>>4)*4+r.
// ---------------------------------------------------------------------------
__global__ __launch_bounds__(512, 4) void logits_fused_kernel(
    const float* __restrict__ features,   // [T][256]
    const float* __restrict__ gumbel,     // [T][2][128]
    const short* __restrict__ BT,         // [2][2][128][128] bf16 bits
    const float* __restrict__ bl,         // [2][128]
    const float* __restrict__ CO,         // [2][128][256]
    const float* __restrict__ b_out,      // [256]
    float* __restrict__ out,              // [T][256]
    float* __restrict__ idx_f,            // [T][2] float-encoded indices
    int* __restrict__ flag_count,
    int* __restrict__ flag_list)
{
    __shared__ int sidx[NG][64];

    const int tid = threadIdx.x;
    const int w   = tid >> 6;     // wave 0..7
    const int l   = tid & 63;
    const int q   = l & 15;       // token slot / A-row selector
    const int h   = l >> 4;       // k-chunk selector / n-subrow
    const int g   = w & 1;
    const int th  = w >> 1;       // 0..3
    const int tblk = blockIdx.x * 64;
    const int t    = tblk + th * 16 + q;

    // ---- prefetch gumbel for this lane's token: n = nt*16 + h*4 + (0..3)
    const float* gp = gumbel + ((size_t)t * NG + g) * NN + h * 4;
    f32x4 gv[8];
#pragma unroll
    for (int nt = 0; nt < 8; ++nt)
        gv[nt] = *reinterpret_cast<const f32x4*>(gp + nt * 16);

    f32x4 acc[8];
#pragma unroll
    for (int nt = 0; nt < 8; ++nt) acc[nt] = (f32x4){0.f, 0.f, 0.f, 0.f};

    const float* fp  = features + (size_t)t * FDIM + g * DDIM + h * 8;
    const short* bp0 = BT + (size_t)g * 16384 + q * 128 + h * 8;

    for (int ks = 0; ks < 4; ++ks) {
        // B-frag: 8 consecutive f32 of this token's features, split exact
        const float4 v0 = *reinterpret_cast<const float4*>(fp + ks * 32);
        const float4 v1 = *reinterpret_cast<const float4*>(fp + ks * 32 + 4);
        const float xs[8] = {v0.x, v0.y, v0.z, v0.w, v1.x, v1.y, v1.z, v1.w};
        short8 B1, B2;
#pragma unroll
        for (int j = 0; j < 8; ++j) {
            const unsigned u = __float_as_uint(xs[j]);
            const float hi = __uint_as_float(u & 0xffff0000u);
            const unsigned u2 = __float_as_uint(xs[j] - hi);
            B1[j] = (short)(u >> 16);
            B2[j] = (short)(u2 >> 16);
        }
        // A-frags: pre-split W^T rows (L2-resident), 3 MFMAs per Mtile
#pragma unroll
        for (int nt = 0; nt < 8; ++nt) {
            const short* ap = bp0 + nt * 16 * 128 + ks * 32;
            const short8 A1 = *reinterpret_cast<const short8*>(ap);
            const short8 A2 = *reinterpret_cast<const short8*>(ap + 32768);
            acc[nt] = __builtin_amdgcn_mfma_f32_16x16x32_bf16(A1, B1, acc[nt], 0, 0, 0);
            acc[nt] = __builtin_amdgcn_mfma_f32_16x16x32_bf16(A2, B1, acc[nt], 0, 0, 0);
            acc[nt] = __builtin_amdgcn_mfma_f32_16x16x32_bf16(A1, B2, acc[nt], 0, 0, 0);
        }
    }

    // ---- epilogue: per-lane top-2 over its 32 n-values (all in registers)
    float m1 = -3.4e38f, m2 = -3.4e38f;
    int   i1 = 0;
#pragma unroll
    for (int nt = 0; nt < 8; ++nt) {
        const f32x4 bv = *reinterpret_cast<const f32x4*>(bl + g * NN + nt * 16 + h * 4);
#pragma unroll
        for (int r = 0; r < 4; ++r) {
            const float v = acc[nt][r] + bv[r] + gv[nt][r];
            const int   n = nt * 16 + h * 4 + r;   // increasing per lane
            if (v > m1) { m2 = m1; m1 = v; i1 = n; }
            else        { m2 = fmaxf(m2, v); }
        }
    }
    // reduce across the 4 lanes (h groups) sharing this token
#pragma unroll
    for (int off = 16; off < 64; off <<= 1) {
        const float om1 = __shfl_xor(m1, off);
        const int   oi1 = __shfl_xor(i1, off);
        const float om2 = __shfl_xor(m2, off);
        if (om1 > m1)      { m2 = fmaxf(m1, om2); m1 = om1; i1 = oi1; }
        else if (om1 < m1) { m2 = fmaxf(m2, om1); }
        else               { m2 = m1; i1 = min(i1, oi1); }
    }
    if (h == 0) {
        idx_f[(size_t)t * NG + g] = (float)i1;
        sidx[g][th * 16 + q] = i1;
        if (m1 - m2 < TAU) {
            const int p = atomicAdd(flag_count, 1);
            if (p < CAP) flag_list[p] = t * NG + g;
        }
    }
    __syncthreads();

    // ---- fused out write: 512 threads cover 64 tokens x 256 e
    const int tok = tid >> 3;        // 0..63
    const int c   = tid & 7;         // float4 phase
    const int tt  = tblk + tok;
    const int j0  = sidx[0][tok];
    const int j1  = sidx[1][tok];
    const float* c0 = CO + (size_t)j0 * EDIM;
    const float* c1 = CO + (size_t)(NN + j1) * EDIM;
    float* op = out + (size_t)tt * EDIM;
#pragma unroll
    for (int jj = 0; jj < 8; ++jj) {
        const int e4 = c + jj * 8;
        const float4 a  = *reinterpret_cast<const float4*>(c0 + e4 * 4);
        const float4 b2 = *reinterpret_cast<const float4*>(c1 + e4 * 4);
        const float4 bo = *reinterpret_cast<const float4*>(b_out + e4 * 4);
        float4 o;
        o.x = a.x + b2.x + bo.x;
        o.y = a.y + b2.y + bo.y;
        o.z = a.z + b2.z + bo.z;
        o.w = a.w + b2.w + bo.w;
        *reinterpret_cast<float4*>(op + e4 * 4) = o;
    }
}

// ---------------------------------------------------------------------------
// Kernel F (fixup): exact sequential-f32 fmaf recompute for flagged (t,g)
// (bitwise reproduces the round-1 engine that matched numpy). Grid 1024 so
// the ~1k flagged entries run concurrently, one wave-pair each.
// ---------------------------------------------------------------------------
__global__ __launch_bounds__(128) void fixup_kernel(
    const float* __restrict__ features,
    const float* __restrict__ gumbel,
    const float* __restrict__ Wl,         // [2][128 k][128 n]
    const float* __restrict__ bl,
    float* __restrict__ idx_f,
    const int* __restrict__ flag_count,
    const int* __restrict__ flag_list)
{
    __shared__ float sm[2];
    __shared__ int   si[2];
    int total = *flag_count;
    if (total > CAP) total = CAP;
    const int n = threadIdx.x;

    for (int e = blockIdx.x; e < total; e += gridDim.x) {
        const int code = flag_list[e];
        const int t = code >> 1, g = code & 1;
        const float* fpr = features + (size_t)t * FDIM + g * DDIM;
        const float* wp  = Wl + (size_t)g * DDIM * NN + n;
        float dot = 0.f;
#pragma unroll 8
        for (int k = 0; k < DDIM; ++k) dot = fmaf(fpr[k], wp[(size_t)k * NN], dot);
        const float v = (dot + bl[g * NN + n]) + gumbel[((size_t)t * NG + g) * NN + n];

        float m = v; int bi = n;
#pragma unroll
        for (int off = 1; off < 64; off <<= 1) {
            const float om = __shfl_xor(m, off);
            const int   ob = __shfl_xor(bi, off);
            if (om > m || (om == m && ob < bi)) { m = om; bi = ob; }
        }
        if ((n & 63) == 0) { sm[n >> 6] = m; si[n >> 6] = bi; }
        __syncthreads();
        if (n == 0) {
            const float mA = sm[0], mB = sm[1];
            const int bA = si[0], bB = si[1];
            const int best = (mB > mA || (mB == mA && bB < bA)) ? bB : bA;
            idx_f[code] = (float)best;
        }
        __syncthreads();
    }
}

// ---------------------------------------------------------------------------
// Kernel X (outfix): rewrite out rows for flagged tokens from FINAL indices.
// Duplicate tokens (both groups flagged) write identical bytes — benign.
// ---------------------------------------------------------------------------
__global__ __launch_bounds__(64) void outfix_kernel(
    const float* __restrict__ CO,
    const float* __restrict__ b_out,
    const float* __restrict__ idx_f,
    const int* __restrict__ flag_count,
    const int* __restrict__ flag_list,
    float* __restrict__ out)
{
    int total = *flag_count;
    if (total > CAP) total = CAP;
    const int c = threadIdx.x;    // 0..63 float4 slots

    for (int e = blockIdx.x; e < total; e += gridDim.x) {
        const int t  = flag_list[e] >> 1;
        const int i0 = (int)idx_f[t * NG + 0];
        const int i1 = (int)idx_f[t * NG + 1];
        const float4 a  = *reinterpret_cast<const float4*>(CO + (size_t)i0 * EDIM + c * 4);
        const float4 b2 = *reinterpret_cast<const float4*>(CO + (size_t)(NN + i1) * EDIM + c * 4);
        const float4 bo = *reinterpret_cast<const float4*>(b_out + c * 4);
        float4 o;
        o.x = a.x + b2.x + bo.x;
        o.y = a.y + b2.y + bo.y;
        o.z = a.z + b2.z + bo.z;
        o.w = a.w + b2.w + bo.w;
        *reinterpret_cast<float4*>(out + (size_t)t * EDIM + c * 4) = o;
    }
}

// ---------------------------------------------------------------------------
extern "C" void kernel_launch(void* const* d_in, const int* in_sizes, int n_in,
                              void* d_out, int out_size, void* d_ws, size_t ws_size,
                              hipStream_t stream) {
    const float* features  = (const float*)d_in[0];  // [32,4096,256]
    const float* gumbel    = (const float*)d_in[1];  // [32,4096,2,128]
    const float* Wl        = (const float*)d_in[2];  // [2,128,128]
    const float* bl        = (const float*)d_in[3];  // [2,128]
    const float* codebooks = (const float*)d_in[4];  // [2,128,128]
    const float* W_out     = (const float*)d_in[5];  // [256,256]
    const float* b_out     = (const float*)d_in[6];  // [256]

    float* out   = (float*)d_out;                    // [T,256]
    float* idx_f = out + (size_t)T_TOTAL * EDIM;     // [T,2] float-encoded indices

    // ws layout: CO (256KB) | BT (128KB) | flag_count (pad 256B) | flag_list (64KB)
    char* ws = (char*)d_ws;
    float* CO         = (float*)ws;                        // 262144 B
    short* BT         = (short*)(ws + 262144);             // 131072 B
    int*   flag_count = (int*)(ws + 262144 + 131072);      // @393216
    int*   flag_list  = (int*)(ws + 393216 + 256);         // @393472, 64KB

    prep_kernel<<<NG * NN, 256, 0, stream>>>(codebooks, W_out, Wl, CO, BT, flag_count);
    logits_fused_kernel<<<T_TOTAL / 64, 512, 0, stream>>>(
        features, gumbel, BT, bl, CO, b_out, out, idx_f, flag_count, flag_list);
    fixup_kernel<<<1024, 128, 0, stream>>>(
        features, gumbel, Wl, bl, idx_f, flag_count, flag_list);
    outfix_kernel<<<1024, 64, 0, stream>>>(
        CO, b_out, idx_f, flag_count, flag_list, out);
}